// Round 4
// baseline (276.403 us; speedup 1.0000x reference)
//
#include <hip/hip_runtime.h>
#include <math.h>

#define BATCH 4
#define NPTS  2048
#define PTS   8192      // BATCH*NPTS
#define NS    64
#define KPTS  15
#define CKP   64
#define FDIM  256
#define HIDD  512
#define NHEAD 8
#define DHEAD 32
#define NLAY  2
#define R2    0.04f
#define KPE   0.08f
#define WIN   0.25f
#define EPSF  1e-5f
#define SCALE 0.17677669529663687f   // 1/sqrt(32)
#define CPITCH 264                   // 256 + 8 pad (bank-safe)

typedef __attribute__((ext_vector_type(8))) short          short8;
typedef __attribute__((ext_vector_type(8))) unsigned short ushort8;
typedef __attribute__((ext_vector_type(4))) float          f32x4;

static __device__ __forceinline__ unsigned short f2bf(float f) {
    unsigned int u = __float_as_uint(f);
    unsigned int r = u + 0x7fffu + ((u >> 16) & 1u);   // RNE
    return (unsigned short)(r >> 16);
}
static __device__ __forceinline__ float b2f(unsigned short u) {
    return __uint_as_float(((unsigned int)u) << 16);
}

// ------------- fused ball query + KPConv: raw [P,64] -------------
__global__ void bkp_k(const float* __restrict__ pos, const float* __restrict__ feat,
                      const float* __restrict__ kpts, const float* __restrict__ kpw,
                      float* __restrict__ raw)
{
    int w = threadIdx.x >> 6, lane = threadIdx.x & 63;
    int p = blockIdx.x * 4 + w;
    int b = p >> 11;
    __shared__ int   nb[4][64];
    __shared__ float wf[4][45];
    __shared__ float kp[45];
    if (threadIdx.x < 45) kp[threadIdx.x] = kpts[threadIdx.x];

    const float* pb = pos + (size_t)b * NPTS * 3;
    float xi = pos[p*3+0], yi = pos[p*3+1], zi = pos[p*3+2];
    int count = 0;
    for (int jc = 0; jc < NPTS; jc += 64) {
        int j = jc + lane;
        float dx = pb[j*3+0] - xi;
        float dy = pb[j*3+1] - yi;
        float dz = pb[j*3+2] - zi;
        float d2 = dx*dx + dy*dy + dz*dz;
        bool within = d2 <= R2;
        unsigned long long m = __ballot(within);
        if (within) {
            int r = count + __popcll(m & ((1ull << lane) - 1ull));
            if (r < NS) nb[w][r] = b*NPTS + j;
        }
        count += __popcll(m);
        if (count >= NS) break;
    }
    int cc = count < NS ? count : NS;
    if (lane >= cc) nb[w][lane] = PTS;
    __syncthreads();

    int id = nb[w][lane];
    bool val = id < PTS;
    float rx, ry, rz, f0, f1, f2;
    if (val) {
        rx = pos[id*3+0] - xi; ry = pos[id*3+1] - yi; rz = pos[id*3+2] - zi;
        f0 = feat[id*3+0]; f1 = feat[id*3+1]; f2 = feat[id*3+2];
    } else {
        rx = 1e6f; ry = 1e6f; rz = 1e6f; f0 = f1 = f2 = 0.f;
    }
    for (int k = 0; k < KPTS; ++k) {
        float dx = rx - kp[k*3+0], dy = ry - kp[k*3+1], dz = rz - kp[k*3+2];
        float dist = sqrtf(dx*dx + dy*dy + dz*dz + 1e-12f);
        float infl = 1.0f - dist / KPE;
        infl = infl > 0.f ? infl : 0.f;
        float v0 = infl*f0, v1 = infl*f1, v2 = infl*f2;
        for (int off = 32; off; off >>= 1) {
            v0 += __shfl_down(v0, off);
            v1 += __shfl_down(v1, off);
            v2 += __shfl_down(v2, off);
        }
        if (lane == 0) { wf[w][k*3+0]=v0; wf[w][k*3+1]=v1; wf[w][k*3+2]=v2; }
    }
    __syncthreads();
    float acc = 0.f;
    for (int t = 0; t < 45; ++t) acc += wf[w][t] * kpw[t*CKP + lane];
    raw[p*CKP + lane] = acc;
}

// ---------------- BN stats ----------------
__global__ void bn_stats_k(const float* __restrict__ raw, float* __restrict__ stats)
{
    int c = blockIdx.x, tid = threadIdx.x;
    float s = 0.f, q = 0.f;
    for (int p = tid; p < PTS; p += 256) { float v = raw[p*CKP + c]; s += v; q += v*v; }
    __shared__ float sh[256], sh2[256];
    sh[tid]=s; sh2[tid]=q; __syncthreads();
    for (int o = 128; o; o >>= 1) { if (tid < o) { sh[tid]+=sh[tid+o]; sh2[tid]+=sh2[tid+o]; } __syncthreads(); }
    if (tid == 0) { stats[c] = sh[0]; stats[CKP + c] = sh2[0]; }
}

// ------- fused cluster: per-batch min, cids, stable counting sort ------------
__global__ void cluster_k(const float* __restrict__ pos, int* __restrict__ sorted,
                          int* __restrict__ inv, int* __restrict__ offs,
                          int* __restrict__ hist)
{
    int b = blockIdx.x, tid = threadIdx.x;
    __shared__ float sx[256], sy[256], sz[256];
    float mx=1e30f, my=1e30f, mz=1e30f;
    for (int n = tid; n < NPTS; n += 256) {
        const float* q = pos + ((size_t)b*NPTS + n)*3;
        mx = fminf(mx, q[0]); my = fminf(my, q[1]); mz = fminf(mz, q[2]);
    }
    sx[tid]=mx; sy[tid]=my; sz[tid]=mz; __syncthreads();
    for (int o=128;o;o>>=1){ if(tid<o){sx[tid]=fminf(sx[tid],sx[tid+o]);sy[tid]=fminf(sy[tid],sy[tid+o]);sz[tid]=fminf(sz[tid],sz[tid+o]);} __syncthreads(); }
    float X = sx[0], Y = sy[0], Z = sz[0];
    __syncthreads();

    __shared__ unsigned char cid_s[NPTS];
    for (int n = tid; n < NPTS; n += 256) {
        const float* q = pos + ((size_t)b*NPTS + n)*3;
        int cx = (int)floorf((q[0]-X)/WIN);
        int cy = (int)floorf((q[1]-Y)/WIN);
        int cz = (int)floorf((q[2]-Z)/WIN);
        cid_s[n] = (unsigned char)((cx<<4) | (cy<<2) | cz);
    }
    __syncthreads();

    int c = tid >> 2, sub = tid & 3;
    int cnt = 0;
    for (int n = sub*512; n < sub*512+512; ++n) cnt += (cid_s[n] == c);
    __shared__ int cnt_s[64][4];
    __shared__ int tot[64], off_c[64];
    cnt_s[c][sub] = cnt; __syncthreads();
    if (tid < 64) tot[tid] = cnt_s[tid][0]+cnt_s[tid][1]+cnt_s[tid][2]+cnt_s[tid][3];
    __syncthreads();
    if (tid == 0) { int run = 0; for (int i = 0; i < 64; ++i) { off_c[i] = run; run += tot[i]; } }
    __syncthreads();
    if (tid < 64) { hist[b*64+tid] = tot[tid]; offs[b*64+tid] = off_c[tid]; }

    int base = off_c[c];
    for (int s = 0; s < sub; ++s) base += cnt_s[c][s];
    int run = 0;
    for (int n = sub*512; n < sub*512+512; ++n) {
        if (cid_s[n] == c) {
            int slot = b*NPTS + base + run;
            int p = b*NPTS + n;
            sorted[slot] = p;
            inv[p] = slot;
            ++run;
        }
    }
}

// ------- BN + LeakyReLU + [pos|kpf] @ Wm -> x written in SORTED order --------
__global__ void embed_k(const float* __restrict__ pos, const float* __restrict__ raw,
                        const float* __restrict__ stats, const float* __restrict__ gamma,
                        const float* __restrict__ beta, const float* __restrict__ Wm,
                        const int* __restrict__ inv,
                        float* __restrict__ xs, unsigned short* __restrict__ xsb)
{
    int p = blockIdx.x, tid = threadIdx.x;
    __shared__ float pw[67];
    if (tid < 3) pw[tid] = pos[p*3 + tid];
    else if (tid < 67) {
        int c = tid - 3;
        float mu  = stats[c] * (1.0f/PTS);
        float var = stats[CKP+c] * (1.0f/PTS) - mu*mu;
        float v = raw[p*CKP + c];
        float h = gamma[c] * (v - mu) * rsqrtf(var + EPSF) + beta[c];
        pw[tid] = h >= 0.f ? h : 0.2f * h;
    }
    __syncthreads();
    float acc = 0.f;
    for (int c = 0; c < 67; ++c) acc += pw[c] * Wm[c*FDIM + tid];
    int slot = inv[p];
    xs[(size_t)slot*FDIM + tid] = acc;
    xsb[(size_t)slot*FDIM + tid] = f2bf(acc);
}

// ---------------- weight convert+transpose: [K][N] f32 -> [N][K] bf16 --------
__global__ void wconv_k(const float* __restrict__ Wq, const float* __restrict__ Wk,
                        const float* __restrict__ Wv, const float* __restrict__ Wo,
                        const float* __restrict__ W1, const float* __restrict__ W2,
                        unsigned short* __restrict__ wT)
{
    int id = blockIdx.z; int t = id >> 1, l = id & 1;
    const float* src; unsigned short* dst; int K, N;
    switch (t) {
        case 0: src=Wq+(size_t)l*65536;  dst=wT+(size_t)l*196608;             K=256; N=256; break;
        case 1: src=Wk+(size_t)l*65536;  dst=wT+(size_t)l*196608+65536;       K=256; N=256; break;
        case 2: src=Wv+(size_t)l*65536;  dst=wT+(size_t)l*196608+131072;      K=256; N=256; break;
        case 3: src=Wo+(size_t)l*65536;  dst=wT+393216+(size_t)l*65536;       K=256; N=256; break;
        case 4: src=W1+(size_t)l*131072; dst=wT+524288+(size_t)l*131072;      K=256; N=512; break;
        default:src=W2+(size_t)l*131072; dst=wT+786432+(size_t)l*131072;      K=512; N=256; break;
    }
    int n0 = blockIdx.x*32, k0 = blockIdx.y*32;
    if (n0 >= N || k0 >= K) return;
    __shared__ float ld[32][33];
    int tid = threadIdx.x;
    #pragma unroll
    for (int i = 0; i < 4; ++i) { int v=tid+i*256; int ty=v>>5, tx=v&31;
        ld[ty][tx] = src[(size_t)(k0+ty)*N + n0+tx]; }
    __syncthreads();
    #pragma unroll
    for (int i = 0; i < 4; ++i) { int v=tid+i*256; int ny=v>>5, nk=v&31;
        dst[(size_t)(n0+ny)*K + k0+nk] = f2bf(ld[nk][ny]); }
}

__global__ void packb_k(const float* __restrict__ bq, const float* __restrict__ bk,
                        const float* __restrict__ bv, float* __restrict__ bqkv)
{
    int l = blockIdx.x, n = threadIdx.x;   // 768 threads
    float v = (n < 256) ? bq[l*256+n] : (n < 512) ? bk[l*256+n-256] : bv[l*256+n-512];
    bqkv[l*768 + n] = v;
}

// ------ wide-tile bf16 MFMA GEMM, 32x256 tile, optional fused LayerNorm ------
// A [PTS][K] bf16, Wt [Nc][K] bf16. 256 threads = 4 waves (wave = 32x64).
// LNM: 0 none, 1 LN (Cf fp32 + Cb bf16), 2 LN final (scatter fp32 via sorted).
template<int ACT, int LNM>
__global__ __launch_bounds__(256) void bgemm256_k(
    const unsigned short* __restrict__ A, const unsigned short* __restrict__ Wt,
    const float* __restrict__ bias, const float* __restrict__ R,
    const float* __restrict__ g, const float* __restrict__ be,
    const int* __restrict__ sorted,
    float* __restrict__ Cf, unsigned short* __restrict__ Cb,
    int Nc, int K)
{
    __shared__ unsigned short As[32*72];
    __shared__ unsigned short Bs[256*72];
    __shared__ float red_s[4][32], red_q[4][32];
    int tid = threadIdx.x;
    int l = tid & 63, wc = tid >> 6;
    int lr = l & 15, lk = l >> 4;
    int bm = blockIdx.y * 32, bn = blockIdx.x * 256;

    f32x4 acc[2][4] = {};

    for (int k0 = 0; k0 < K; k0 += 64) {
        __syncthreads();
        {
            int row = tid >> 3, seg = tid & 7;
            *(ushort8*)&As[row*72 + seg*8] =
                *(const ushort8*)&A[(size_t)(bm + row)*K + k0 + seg*8];
        }
        #pragma unroll
        for (int i = 0; i < 8; ++i) {
            int id = tid + i*256;
            int row = id >> 3, seg = id & 7;
            *(ushort8*)&Bs[row*72 + seg*8] =
                *(const ushort8*)&Wt[(size_t)(bn + row)*K + k0 + seg*8];
        }
        __syncthreads();
        #pragma unroll
        for (int kk = 0; kk < 64; kk += 32) {
            short8 a[2], b[4];
            #pragma unroll
            for (int mi = 0; mi < 2; ++mi)
                a[mi] = *(const short8*)&As[(mi*16 + lr)*72 + kk + lk*8];
            #pragma unroll
            for (int ni = 0; ni < 4; ++ni)
                b[ni] = *(const short8*)&Bs[(wc*64 + ni*16 + lr)*72 + kk + lk*8];
            #pragma unroll
            for (int mi = 0; mi < 2; ++mi)
                #pragma unroll
                for (int ni = 0; ni < 4; ++ni)
                    acc[mi][ni] = __builtin_amdgcn_mfma_f32_16x16x32_bf16(
                        a[mi], b[ni], acc[mi][ni], 0, 0, 0);
        }
    }

    // epilogue: v = acc + bias (+R) (+relu), in place
    #pragma unroll
    for (int mi = 0; mi < 2; ++mi) {
        #pragma unroll
        for (int r = 0; r < 4; ++r) {
            int row = bm + mi*16 + lk*4 + r;
            #pragma unroll
            for (int ni = 0; ni < 4; ++ni) {
                int col = bn + wc*64 + ni*16 + lr;
                float v = acc[mi][ni][r] + bias[col];
                if (R) v += R[(size_t)row*Nc + col];
                if (ACT == 1) v = v > 0.f ? v : 0.f;
                acc[mi][ni][r] = v;
            }
        }
    }

    if (LNM == 0) {
        #pragma unroll
        for (int mi = 0; mi < 2; ++mi)
            #pragma unroll
            for (int r = 0; r < 4; ++r) {
                int row = bm + mi*16 + lk*4 + r;
                #pragma unroll
                for (int ni = 0; ni < 4; ++ni) {
                    int col = bn + wc*64 + ni*16 + lr;
                    if (Cf) Cf[(size_t)row*Nc + col] = acc[mi][ni][r];
                    if (Cb) Cb[(size_t)row*Nc + col] = f2bf(acc[mi][ni][r]);
                }
            }
    } else {
        // fused LayerNorm over full rows (Nc == 256, bn == 0)
        #pragma unroll
        for (int mi = 0; mi < 2; ++mi) {
            #pragma unroll
            for (int r = 0; r < 4; ++r) {
                float ps = 0.f, pq = 0.f;
                #pragma unroll
                for (int ni = 0; ni < 4; ++ni) { float v = acc[mi][ni][r]; ps += v; pq += v*v; }
                ps += __shfl_xor(ps, 1);  pq += __shfl_xor(pq, 1);
                ps += __shfl_xor(ps, 2);  pq += __shfl_xor(pq, 2);
                ps += __shfl_xor(ps, 4);  pq += __shfl_xor(pq, 4);
                ps += __shfl_xor(ps, 8);  pq += __shfl_xor(pq, 8);
                if (lr == 0) {
                    int rl = mi*16 + lk*4 + r;
                    red_s[wc][rl] = ps;
                    red_q[wc][rl] = pq;
                }
            }
        }
        __syncthreads();
        #pragma unroll
        for (int mi = 0; mi < 2; ++mi) {
            #pragma unroll
            for (int r = 0; r < 4; ++r) {
                int rl = mi*16 + lk*4 + r;
                float s = red_s[0][rl] + red_s[1][rl] + red_s[2][rl] + red_s[3][rl];
                float q = red_q[0][rl] + red_q[1][rl] + red_q[2][rl] + red_q[3][rl];
                float mu  = s * (1.0f/FDIM);
                float var = q * (1.0f/FDIM) - mu*mu;
                float rs  = rsqrtf(var + EPSF);
                int row = bm + rl;
                #pragma unroll
                for (int ni = 0; ni < 4; ++ni) {
                    int col = wc*64 + ni*16 + lr;
                    float o = g[col]*(acc[mi][ni][r]-mu)*rs + be[col];
                    if (LNM == 2) Cf[(size_t)sorted[row]*FDIM + col] = o;
                    else          Cf[(size_t)row*FDIM + col] = o;
                    if (Cb) Cb[(size_t)row*FDIM + col] = f2bf(o);
                }
            }
        }
    }
}

// ---------------- cluster-local MFMA attention ----------------
__global__ __launch_bounds__(512) void attn_k(
    const unsigned short* __restrict__ qkv, const int* __restrict__ offs,
    const int* __restrict__ hist, unsigned short* __restrict__ o)
{
    int cci = blockIdx.x, b = blockIdx.y;
    int Mc = hist[b*64 + cci];
    if (Mc == 0) return;
    int off = b*NPTS + offs[b*64 + cci];
    __shared__ unsigned short Kl[64*CPITCH];
    __shared__ unsigned short Vl[64*CPITCH];
    __shared__ unsigned short Pl[8][64*72];
    int tid = threadIdx.x;

    if (Mc <= 64) {
        #pragma unroll
        for (int it = 0; it < 4; ++it) {
            int id = tid + it*512;
            int key = id >> 5, ch8 = (id & 31)*8;
            ushort8 kv, vv;
            if (key < Mc) {
                kv = *(const ushort8*)&qkv[(size_t)(off+key)*768 + 256 + ch8];
                vv = *(const ushort8*)&qkv[(size_t)(off+key)*768 + 512 + ch8];
            } else {
                kv = (ushort8)0; vv = (ushort8)0;
            }
            *(ushort8*)&Kl[key*CPITCH + ch8] = kv;
            *(ushort8*)&Vl[key*CPITCH + ch8] = vv;
        }
        __syncthreads();

        int w = tid >> 6, l = tid & 63;
        int h = w;
        int lr = l & 15, lk = l >> 4;

        f32x4 s[4][4] = {};
        short8 a[4], bb[4];
        #pragma unroll
        for (int mi = 0; mi < 4; ++mi) {
            int rg = off + mi*16 + lr;
            if (rg > PTS-1) rg = PTS-1;
            a[mi] = *(const short8*)&qkv[(size_t)rg*768 + h*32 + lk*8];
        }
        #pragma unroll
        for (int ni = 0; ni < 4; ++ni)
            bb[ni] = *(const short8*)&Kl[(ni*16+lr)*CPITCH + h*32 + lk*8];
        #pragma unroll
        for (int mi = 0; mi < 4; ++mi)
            #pragma unroll
            for (int ni = 0; ni < 4; ++ni)
                s[mi][ni] = __builtin_amdgcn_mfma_f32_16x16x32_bf16(a[mi], bb[ni], s[mi][ni], 0, 0, 0);

        unsigned short* Pw = Pl[w];
        float invl[4][4];
        #pragma unroll
        for (int mi = 0; mi < 4; ++mi) {
            #pragma unroll
            for (int r = 0; r < 4; ++r) {
                int row = mi*16 + lk*4 + r;
                float sv[4]; float mx = -1e30f;
                #pragma unroll
                for (int ni = 0; ni < 4; ++ni) {
                    int col = ni*16 + lr;
                    float x = s[mi][ni][r] * SCALE;
                    sv[ni] = (col < Mc) ? x : -1e30f;
                    mx = fmaxf(mx, sv[ni]);
                }
                mx = fmaxf(mx, __shfl_xor(mx, 1));
                mx = fmaxf(mx, __shfl_xor(mx, 2));
                mx = fmaxf(mx, __shfl_xor(mx, 4));
                mx = fmaxf(mx, __shfl_xor(mx, 8));
                float ls = 0.f;
                #pragma unroll
                for (int ni = 0; ni < 4; ++ni) {
                    float e = __expf(sv[ni] - mx);
                    ls += e;
                    Pw[row*72 + ni*16 + lr] = f2bf(e);
                }
                ls += __shfl_xor(ls, 1);
                ls += __shfl_xor(ls, 2);
                ls += __shfl_xor(ls, 4);
                ls += __shfl_xor(ls, 8);
                invl[mi][r] = 1.0f / ls;
            }
        }

        f32x4 oacc[4][2] = {};
        #pragma unroll
        for (int ks = 0; ks < 2; ++ks) {
            short8 bv[2];
            #pragma unroll
            for (int db = 0; db < 2; ++db) {
                short8 t;
                #pragma unroll
                for (int e = 0; e < 8; ++e)
                    t[e] = (short)Vl[(ks*32 + lk*8 + e)*CPITCH + h*32 + db*16 + lr];
                bv[db] = t;
            }
            #pragma unroll
            for (int mi = 0; mi < 4; ++mi) {
                short8 pa = *(const short8*)&Pw[(mi*16+lr)*72 + ks*32 + lk*8];
                #pragma unroll
                for (int db = 0; db < 2; ++db)
                    oacc[mi][db] = __builtin_amdgcn_mfma_f32_16x16x32_bf16(pa, bv[db], oacc[mi][db], 0, 0, 0);
            }
        }

        #pragma unroll
        for (int mi = 0; mi < 4; ++mi)
            #pragma unroll
            for (int db = 0; db < 2; ++db)
                #pragma unroll
                for (int r = 0; r < 4; ++r) {
                    int row = mi*16 + lk*4 + r;
                    if (row < Mc)
                        o[(size_t)(off+row)*FDIM + h*32 + db*16 + lr] =
                            f2bf(oacc[mi][db][r] * invl[mi][r]);
                }
    } else {
        for (int task = tid; task < Mc*NHEAD; task += 512) {
            int row = task >> 3, h = task & 7;
            float qr[DHEAD];
            #pragma unroll
            for (int d = 0; d < DHEAD; ++d)
                qr[d] = b2f(qkv[(size_t)(off+row)*768 + h*32 + d]);
            float m = -3e38f, lsum = 0.f, acc[DHEAD];
            #pragma unroll
            for (int d = 0; d < DHEAD; ++d) acc[d] = 0.f;
            for (int j = 0; j < Mc; ++j) {
                float dot = 0.f;
                #pragma unroll
                for (int d = 0; d < DHEAD; ++d)
                    dot += qr[d] * b2f(qkv[(size_t)(off+j)*768 + 256 + h*32 + d]);
                float sc = dot * SCALE;
                float mn = fmaxf(m, sc);
                float aa = __expf(m - mn);
                float e  = __expf(sc - mn);
                lsum = lsum*aa + e;
                #pragma unroll
                for (int d = 0; d < DHEAD; ++d)
                    acc[d] = acc[d]*aa + e * b2f(qkv[(size_t)(off+j)*768 + 512 + h*32 + d]);
                m = mn;
            }
            float inv = 1.0f / lsum;
            #pragma unroll
            for (int d = 0; d < DHEAD; ++d)
                o[(size_t)(off+row)*FDIM + h*32 + d] = f2bf(acc[d]*inv);
        }
    }
}

extern "C" void kernel_launch(void* const* d_in, const int* in_sizes, int n_in,
                              void* d_out, int out_size, void* d_ws, size_t ws_size,
                              hipStream_t stream)
{
    (void)in_sizes; (void)n_in; (void)out_size; (void)ws_size;
    const float* pos  = (const float*)d_in[0];
    const float* feat = (const float*)d_in[1];
    const float* kpts = (const float*)d_in[2];
    const float* kpw  = (const float*)d_in[3];
    const float* bn_g = (const float*)d_in[4];
    const float* bn_b = (const float*)d_in[5];
    const float* Wm   = (const float*)d_in[6];
    const float* Wq   = (const float*)d_in[7];
    const float* bq   = (const float*)d_in[8];
    const float* Wk   = (const float*)d_in[9];
    const float* bk   = (const float*)d_in[10];
    const float* Wv   = (const float*)d_in[11];
    const float* bv   = (const float*)d_in[12];
    const float* Wo   = (const float*)d_in[13];
    const float* bo   = (const float*)d_in[14];
    const float* g1   = (const float*)d_in[15];
    const float* be1  = (const float*)d_in[16];
    const float* W1   = (const float*)d_in[17];
    const float* bb1  = (const float*)d_in[18];
    const float* W2   = (const float*)d_in[19];
    const float* bb2  = (const float*)d_in[20];
    const float* g2   = (const float*)d_in[21];
    const float* be2  = (const float*)d_in[22];

    char* ws = (char*)d_ws;
    const size_t MB = 1024*1024;
    float* raw    = (float*)(ws + 0);                    // 2 MB
    float* stats  = (float*)(ws + 2*MB);                 // 512 B
    int*   hist   = (int*)(ws + 2*MB + 4096);            // 1 KB
    int*   offs   = hist + 256;
    int*   sorted = (int*)(ws + 2*MB + 16384);           // 32 KB
    int*   inv    = sorted + PTS;                        // 32 KB
    float* xs   = (float*)(ws + 5*MB);                   // [P,256] f32 (8 MB)
    float* x2   = (float*)(ws + 13*MB);                  // [P,256] f32 (8 MB)
    unsigned short* xsb   = (unsigned short*)(ws + 21*MB);  // [P,256] bf16 (4 MB)
    unsigned short* x2b   = (unsigned short*)(ws + 25*MB);  // [P,256] bf16 (4 MB)
    unsigned short* qkvb  = (unsigned short*)(ws + 29*MB);  // [P,768] bf16 (12 MB)
    unsigned short* attnb = (unsigned short*)(ws + 41*MB);  // [P,256] bf16 (4 MB)
    unsigned short* wT    = (unsigned short*)(ws + 45*MB);  // 2 MB
    float*          bqkv  = (float*)(ws + 47*MB);           // 6 KB
    unsigned short* hb    = qkvb;                            // [P,512] aliases qkv (dead)

    wconv_k<<<dim3(16,16,12), 256, 0, stream>>>(Wq, Wk, Wv, Wo, W1, W2, wT);
    packb_k<<<NLAY, 768, 0, stream>>>(bq, bk, bv, bqkv);
    cluster_k<<<BATCH, 256, 0, stream>>>(pos, sorted, inv, offs, hist);
    bkp_k<<<PTS/4, 256, 0, stream>>>(pos, feat, kpts, kpw, raw);
    bn_stats_k<<<CKP, 256, 0, stream>>>(raw, stats);
    embed_k<<<PTS, 256, 0, stream>>>(pos, raw, stats, bn_g, bn_b, Wm, inv, xs, xsb);

    for (int l = 0; l < NLAY; ++l) {
        // fused QKV projection: [P,256] @ [256,768] -> qkvb
        bgemm256_k<0,0><<<dim3(3, PTS/32), 256, 0, stream>>>(
            xsb, wT + (size_t)l*196608, bqkv + l*768, nullptr, nullptr, nullptr, nullptr,
            nullptr, qkvb, 768, FDIM);
        attn_k<<<dim3(64, BATCH), 512, 0, stream>>>(qkvb, offs, hist, attnb);
        // O-proj + residual + LN1 -> x2 (f32) + x2b (bf16)
        bgemm256_k<0,1><<<dim3(1, PTS/32), 256, 0, stream>>>(
            attnb, wT + 393216 + (size_t)l*65536, bo + l*FDIM, xs,
            g1 + l*FDIM, be1 + l*FDIM, nullptr, x2, x2b, FDIM, FDIM);
        // FFN1 + relu -> hb (bf16)
        bgemm256_k<1,0><<<dim3(2, PTS/32), 256, 0, stream>>>(
            x2b, wT + 524288 + (size_t)l*131072, bb1 + l*HIDD, nullptr, nullptr, nullptr,
            nullptr, nullptr, hb, HIDD, FDIM);
        // FFN2 + residual + LN2 -> xs/xsb (or scatter to d_out)
        if (l == NLAY-1)
            bgemm256_k<0,2><<<dim3(1, PTS/32), 256, 0, stream>>>(
                hb, wT + 786432 + (size_t)l*131072, bb2 + l*FDIM, x2,
                g2 + l*FDIM, be2 + l*FDIM, sorted, (float*)d_out, nullptr, FDIM, HIDD);
        else
            bgemm256_k<0,1><<<dim3(1, PTS/32), 256, 0, stream>>>(
                hb, wT + 786432 + (size_t)l*131072, bb2 + l*FDIM, x2,
                g2 + l*FDIM, be2 + l*FDIM, nullptr, xs, xsb, FDIM, HIDD);
    }
}